// Round 11
// baseline (182.540 us; speedup 1.0000x reference)
//
#include <hip/hip_runtime.h>
#include <hip/hip_fp16.h>
#include <math.h>

#define N_NODES   50000
#define N_EDGES   400000
#define NCH       16
#define CAP       48          // per-node edge capacity; P(deg>48 | lambda=8) ~ 1e-17
#define EBUF_PAD  16          // slack slots so in-loop record prefetch never reads OOB
#define NSTRIPE   8
#define TPB       256
#define NBN       ((N_NODES + TPB - 1) / TPB)   // 196
#define NB_EDGES  ((N_EDGES + TPB - 1) / TPB)   // 1563
#define NB_PACK   ((N_NODES * NCH + TPB - 1) / TPB)  // 3125
#define NB_PREP   (NB_PACK + NB_EDGES)               // 4688
#define NB_MAIN   3125        // persistent: 12500 waves, 4 nodes/wave (stride 12500)

// ======================= FAST PATH (bucketed, 3 dispatches) =======================

// K0+K1 fused: blocks [0,NB_PACK) pack h into fp16 records; blocks
// [NB_PACK,NB_PREP) do per-edge geometry + bucket write.
__global__ void prep_kernel(const float* __restrict__ h0,
                            const float* __restrict__ h1,
                            const float* __restrict__ h2,
                            const float* __restrict__ pos,
                            const int* __restrict__ src,
                            const int* __restrict__ dst,
                            float4* __restrict__ hpack,
                            float* __restrict__ dists,
                            int* __restrict__ cnt,
                            int2* __restrict__ ebuf) {
    int b = blockIdx.x;
    if (b < NB_PACK) {
        int nk = b * TPB + threadIdx.x;
        if (nk >= N_NODES * NCH) return;
        union { __half h[16]; float4 f[2]; } u;
        u.h[0] = __float2half(h0[nk]);
        const float* p1 = h1 + (size_t)nk * 3;
        u.h[1] = __float2half(p1[0]);
        u.h[2] = __float2half(p1[1]);
        u.h[3] = __float2half(p1[2]);
        const float* p2 = h2 + (size_t)nk * 9;
#pragma unroll
        for (int q = 0; q < 9; ++q) u.h[4 + q] = __float2half(p2[q]);
        u.h[13] = __half(0.0f);
        u.h[14] = __half(0.0f);
        u.h[15] = __half(0.0f);
        float4* o = hpack + (size_t)nk * 2;
        o[0] = u.f[0];
        o[1] = u.f[1];
    } else {
        int e = (b - NB_PACK) * TPB + threadIdx.x;
        if (e >= N_EDGES) return;
        int s = src[e];
        int d = dst[e];
        float rx = pos[3 * s + 0] - pos[3 * d + 0];
        float ry = pos[3 * s + 1] - pos[3 * d + 1];
        float rz = pos[3 * s + 2] - pos[3 * d + 2];
        float dist = sqrtf(rx * rx + ry * ry + rz * rz);
        dists[e] = dist;
        int slot = atomicAdd(&cnt[s], 1);
        if (slot < CAP) {
            ebuf[s * CAP + slot] = make_int2(e, d);
        }
    }
}

// standalone build (tier B path, no hpack)
__global__ void build_kernel(const float* __restrict__ pos,
                             const int* __restrict__ src,
                             const int* __restrict__ dst,
                             float* __restrict__ dists,
                             int* __restrict__ cnt,
                             int2* __restrict__ ebuf) {
    int e = blockIdx.x * TPB + threadIdx.x;
    if (e >= N_EDGES) return;
    int s = src[e];
    int d = dst[e];
    float rx = pos[3 * s + 0] - pos[3 * d + 0];
    float ry = pos[3 * s + 1] - pos[3 * d + 1];
    float rz = pos[3 * s + 2] - pos[3 * d + 2];
    float dist = sqrtf(rx * rx + ry * ry + rz * rz);
    dists[e] = dist;
    int slot = atomicAdd(&cnt[s], 1);
    if (slot < CAP) {
        ebuf[s * CAP + slot] = make_int2(e, d);
    }
}

// ---- per-edge math, FACTORED form (verified round 7) ----
__device__ __forceinline__ void edge_math(
    float ux, float uy, float uz, float R,
    float A0, const float A1[3], const float A2[9],
    float& acc0, float acc1[3], float acc2[9])
{
    float u[3] = {ux, uy, uz};
    float d1 = A1[0] * ux + A1[1] * uy + A1[2] * uz;   // A1.u
    float tA = A2[0] + A2[4] + A2[8];                   // tr(A2)
    float v0 = A2[0] * ux + A2[1] * uy + A2[2] * uz;    // A2 u
    float v1 = A2[3] * ux + A2[4] * uy + A2[5] * uz;
    float v2 = A2[6] * ux + A2[7] * uy + A2[8] * uz;
    float w0 = A2[0] * ux + A2[3] * uy + A2[6] * uz;    // A2^T u
    float w1 = A2[1] * ux + A2[4] * uy + A2[7] * uz;
    float w2 = A2[2] * ux + A2[5] * uy + A2[8] * uz;
    float q = ux * v0 + uy * v1 + uz * v2;              // u^T A2 u

    acc0 += R * (2.0f * A0 + d1 + 2.0f * tA + 2.0f * q);

    float svw[3] = {v0 + w0, v1 + w1, v2 + w2};
    float R2 = R + R;
    float a0t = A0 + tA;
    float Rc1 = R * (a0t + 2.0f * d1);
#pragma unroll
    for (int mm = 0; mm < 3; ++mm) {
        acc1[mm] = fmaf(Rc1, u[mm], acc1[mm]);
        acc1[mm] = fmaf(R2, A1[mm], acc1[mm]);
        acc1[mm] = fmaf(R, svw[mm], acc1[mm]);
    }
#pragma unroll
    for (int mm = 0; mm < 3; ++mm) {
        float t1 = fmaf(2.0f, svw[mm], A1[mm]);
        float g = R * fmaf(a0t, u[mm], t1);
#pragma unroll
        for (int nn = 0; nn < 3; ++nn) {
            float a = acc2[3 * mm + nn];
            a = fmaf(g, u[nn], a);
            a = fmaf(R2, A2[3 * mm + nn], a);
            acc2[3 * mm + nn] = a;
        }
    }
}

// ---- fallback-path helpers ----
__device__ __forceinline__ void load_hset(
    const float* __restrict__ h0, const float* __restrict__ h1,
    const float* __restrict__ h2, const float* __restrict__ dists,
    int d, int e, int k,
    float& A0, float A1[3], float A2[9], float& r, float& nf)
{
    A0 = h0[d * NCH + k];
    const float* p1 = h1 + ((size_t)d * NCH + k) * 3;
    A1[0] = p1[0]; A1[1] = p1[1]; A1[2] = p1[2];
    const float* p2 = h2 + ((size_t)d * NCH + k) * 9;
#pragma unroll
    for (int q2 = 0; q2 < 9; ++q2) A2[q2] = p2[q2];
    unsigned f = (unsigned)e * NCH + (unsigned)k;
    unsigned n_idx = f / (unsigned)N_EDGES;
    unsigned e_idx = f - n_idx * (unsigned)N_EDGES;
    r = dists[e_idx];
    nf = (float)(n_idx + 1);
}

__device__ __forceinline__ float radial_R(float nf, float r) {
    return 0.44721359549995794f * __sinf(nf * 0.3141592653589793f * r) / r;
}

// K2 (tier A): PERSISTENT waves, 4 nodes per wave (grid-stride 12500).
// Cross-node pipeline: next node's meta (cnt + first records + pos) issues
// before the current node's compute, hiding the node-entry serial chain.
// Paired edges per iteration (c, c+4; stride 8); invalid edge B clamps
// indices to node 0 (L2-hot), zero-gates through R, and clamps s2 (NaN guard).
__global__ void node_wave_fast(const float4* __restrict__ hp,
                               const float* __restrict__ pos,
                               const int* __restrict__ cnt,
                               const int2* __restrict__ ebuf,
                               const float* __restrict__ dists,
                               float* __restrict__ out0,
                               float* __restrict__ out1,
                               float* __restrict__ out2) {
    int lane = threadIdx.x & 63;
    int k = lane & 15;
    int j = lane >> 4;
    int wid = (blockIdx.x * TPB + threadIdx.x) >> 6;
    const int NW = NB_MAIN * (TPB >> 6);      // 12500 waves
    if (wid >= N_NODES) return;

    // entry loads for first node (all independent)
    int node = wid;
    int base = node * CAP;
    int m = cnt[node];
    int2 pkA = ebuf[base + j];         // slot j   (always in row)
    int2 pkB = ebuf[base + j + 4];     // slot j+4 (always in row)
    float ps0 = pos[3 * node + 0];
    float ps1 = pos[3 * node + 1];
    float ps2 = pos[3 * node + 2];

    for (;;) {
        // ---- issue NEXT node's meta now; resolves under this node's compute ----
        int nnode = node + NW;
        bool hasNext = (nnode < N_NODES);
        int pn = hasNext ? nnode : node;   // clamped, unconditional loads
        int pbase = pn * CAP;
        int m_n = cnt[pn];
        int2 pkA_n = ebuf[pbase + j];
        int2 pkB_n = ebuf[pbase + j + 4];
        float qs0 = pos[3 * pn + 0];
        float qs1 = pos[3 * pn + 1];
        float qs2 = pos[3 * pn + 2];

        int mc = m;
        if (mc > CAP) mc = CAP;

        float acc0 = 0.0f;
        float acc1[3] = {0.0f, 0.0f, 0.0f};
        float acc2[9] = {0.0f, 0.0f, 0.0f, 0.0f, 0.0f, 0.0f, 0.0f, 0.0f, 0.0f};

        int2 eA = pkA;
        int2 eB = pkB;
        int c = j;
        while (c < mc) {
            // prefetch next pair's records (EBUF_PAD keeps base+c+12 readable)
            int2 eA_n = ebuf[base + c + 8];
            int2 eB_n = ebuf[base + c + 12];

            bool vb = (c + 4) < mc;        // edge A valid by loop condition
            int da = eA.y;
            int ea = eA.x;
            int db = vb ? eB.y : 0;        // clamp -> node 0 / edge 0 (L2-hot)
            int eb = vb ? eB.x : 0;

            // issue BOTH gather sets now (concurrent in flight)
            size_t ha = ((size_t)((da << 4) | k)) * 2;
            size_t hb = ((size_t)((db << 4) | k)) * 2;
            union { float4 f[2]; __half h[16]; } ua;
            union { float4 f[2]; __half h[16]; } ub;
            ua.f[0] = hp[ha + 0];
            ua.f[1] = hp[ha + 1];
            ub.f[0] = hp[hb + 0];
            ub.f[1] = hp[hb + 1];
            float pa0 = pos[3 * da + 0], pa1 = pos[3 * da + 1], pa2 = pos[3 * da + 2];
            float pb0 = pos[3 * db + 0], pb1 = pos[3 * db + 1], pb2 = pos[3 * db + 2];

            unsigned fA = (unsigned)ea * NCH + (unsigned)k;
            unsigned nA = fA / (unsigned)N_EDGES;
            float rA = dists[fA - nA * (unsigned)N_EDGES];
            unsigned fB = (unsigned)eb * NCH + (unsigned)k;
            unsigned nB = fB / (unsigned)N_EDGES;
            float rB = dists[fB - nB * (unsigned)N_EDGES];

            // ---- edge A (always valid: loop condition is per-lane) ----
            {
                float R = 0.44721359549995794f *
                          __sinf((float)(nA + 1) * 0.3141592653589793f * rA) *
                          __builtin_amdgcn_rcpf(rA);
                float rx = ps0 - pa0;
                float ry = ps1 - pa1;
                float rz = ps2 - pa2;
                float inv = __builtin_amdgcn_rsqf(rx * rx + ry * ry + rz * rz);
                float A0 = __half2float(ua.h[0]);
                float A1[3] = {__half2float(ua.h[1]), __half2float(ua.h[2]),
                               __half2float(ua.h[3])};
                float A2[9];
#pragma unroll
                for (int q2 = 0; q2 < 9; ++q2) A2[q2] = __half2float(ua.h[4 + q2]);
                edge_math(rx * inv, ry * inv, rz * inv, R, A0, A1, A2,
                          acc0, acc1, acc2);
            }
            // ---- edge B (zero-gated through R; s2 clamped so u stays finite) ----
            {
                float R = 0.44721359549995794f *
                          __sinf((float)(nB + 1) * 0.3141592653589793f * rB) *
                          __builtin_amdgcn_rcpf(rB);
                R = vb ? R : 0.0f;
                float rx = ps0 - pb0;
                float ry = ps1 - pb1;
                float rz = ps2 - pb2;
                float s2 = rx * rx + ry * ry + rz * rz;
                s2 = vb ? s2 : 1.0f;       // NaN guard (0*NaN==NaN was the r8 bug)
                float inv = __builtin_amdgcn_rsqf(s2);
                float A0 = __half2float(ub.h[0]);
                float A1[3] = {__half2float(ub.h[1]), __half2float(ub.h[2]),
                               __half2float(ub.h[3])};
                float A2[9];
#pragma unroll
                for (int q2 = 0; q2 < 9; ++q2) A2[q2] = __half2float(ub.h[4 + q2]);
                edge_math(rx * inv, ry * inv, rz * inv, R, A0, A1, A2,
                          acc0, acc1, acc2);
            }

            eA = eA_n;
            eB = eB_n;
            c += 8;
        }

        // reduce across j (lanes xor 16, xor 32)
        acc0 += __shfl_xor(acc0, 16, 64);
        acc0 += __shfl_xor(acc0, 32, 64);
#pragma unroll
        for (int mm = 0; mm < 3; ++mm) {
            acc1[mm] += __shfl_xor(acc1[mm], 16, 64);
            acc1[mm] += __shfl_xor(acc1[mm], 32, 64);
        }
#pragma unroll
        for (int mm = 0; mm < 9; ++mm) {
            acc2[mm] += __shfl_xor(acc2[mm], 16, 64);
            acc2[mm] += __shfl_xor(acc2[mm], 32, 64);
        }

        if (j == 0) {
            int t = node * NCH + k;
            out0[t] = acc0;
            float* o1p = out1 + (size_t)t * 3;
#pragma unroll
            for (int mm = 0; mm < 3; ++mm) o1p[mm] = acc1[mm];
            float* o2p = out2 + (size_t)t * 9;
#pragma unroll
            for (int mm = 0; mm < 9; ++mm) o2p[mm] = acc2[mm];
        }

        if (!hasNext) break;
        node = nnode;
        base = pbase;
        m = m_n;
        pkA = pkA_n;
        pkB = pkB_n;
        ps0 = qs0;
        ps1 = qs1;
        ps2 = qs2;
    }
}

// K2 (tier B): round-3 kernel — unpacked fp32 gather, smaller workspaces.
__global__ void node_wave_mid(const float* __restrict__ h0,
                              const float* __restrict__ h1,
                              const float* __restrict__ h2,
                              const float* __restrict__ pos,
                              const int* __restrict__ cnt,
                              const int2* __restrict__ ebuf,
                              const float* __restrict__ dists,
                              float* __restrict__ out0,
                              float* __restrict__ out1,
                              float* __restrict__ out2) {
    int gid = blockIdx.x * TPB + threadIdx.x;
    int node = gid >> 6;
    if (node >= N_NODES) return;
    int lane = threadIdx.x & 63;
    int k = lane & 15;
    int j = lane >> 4;
    int base = node * CAP;

    int m = cnt[node];
    int2 pk = ebuf[base + j];
    float ps0 = pos[3 * node + 0];
    float ps1 = pos[3 * node + 1];
    float ps2 = pos[3 * node + 2];
    if (m > CAP) m = CAP;

    float acc0 = 0.0f;
    float acc1[3] = {0.0f, 0.0f, 0.0f};
    float acc2[9] = {0.0f, 0.0f, 0.0f, 0.0f, 0.0f, 0.0f, 0.0f, 0.0f, 0.0f};

    int c = j;
    while (c < m) {
        int cn = c + 4;
        int2 pkn = pk;
        if (cn < m) pkn = ebuf[base + cn];

        int e = pk.x;
        int d = pk.y;

        float pd0 = pos[3 * d + 0];
        float pd1 = pos[3 * d + 1];
        float pd2 = pos[3 * d + 2];

        float A0 = h0[d * NCH + k];
        const float* a1p = h1 + ((size_t)d * NCH + k) * 3;
        float A1[3] = {a1p[0], a1p[1], a1p[2]};
        const float* a2p = h2 + ((size_t)d * NCH + k) * 9;
        float A2[9];
#pragma unroll
        for (int q2 = 0; q2 < 9; ++q2) A2[q2] = a2p[q2];

        unsigned f = (unsigned)e * NCH + (unsigned)k;
        unsigned n_idx = f / (unsigned)N_EDGES;
        unsigned e_idx = f - n_idx * (unsigned)N_EDGES;
        float r = dists[e_idx];
        float R = 0.44721359549995794f *
                  __sinf((float)(n_idx + 1) * 0.3141592653589793f * r) / r;

        float rx = ps0 - pd0;
        float ry = ps1 - pd1;
        float rz = ps2 - pd2;
        float dist = sqrtf(rx * rx + ry * ry + rz * rz);
        float inv = 1.0f / dist;

        edge_math(rx * inv, ry * inv, rz * inv, R, A0, A1, A2, acc0, acc1, acc2);

        pk = pkn;
        c = cn;
    }

    acc0 += __shfl_xor(acc0, 16, 64);
    acc0 += __shfl_xor(acc0, 32, 64);
#pragma unroll
    for (int mm = 0; mm < 3; ++mm) {
        acc1[mm] += __shfl_xor(acc1[mm], 16, 64);
        acc1[mm] += __shfl_xor(acc1[mm], 32, 64);
    }
#pragma unroll
    for (int mm = 0; mm < 9; ++mm) {
        acc2[mm] += __shfl_xor(acc2[mm], 16, 64);
        acc2[mm] += __shfl_xor(acc2[mm], 32, 64);
    }

    if (j == 0) {
        int t = node * NCH + k;
        out0[t] = acc0;
        float* o1p = out1 + (size_t)t * 3;
#pragma unroll
        for (int mm = 0; mm < 3; ++mm) o1p[mm] = acc1[mm];
        float* o2p = out2 + (size_t)t * 9;
#pragma unroll
        for (int mm = 0; mm < 9; ++mm) o2p[mm] = acc2[mm];
    }
}

// ======================= FALLBACK (R8 pipeline, small ws) =======================

__global__ void fb_geom_hist(const float* __restrict__ pos,
                             const int* __restrict__ src,
                             const int* __restrict__ dst,
                             float* __restrict__ dists,
                             int* __restrict__ cnt8,
                             int* __restrict__ rankArr) {
    int e = blockIdx.x * TPB + threadIdx.x;
    if (e >= N_EDGES) return;
    int stripe = blockIdx.x & (NSTRIPE - 1);
    int s = src[e];
    int d = dst[e];
    float rx = pos[3 * s + 0] - pos[3 * d + 0];
    float ry = pos[3 * s + 1] - pos[3 * d + 1];
    float rz = pos[3 * s + 2] - pos[3 * d + 2];
    dists[e] = sqrtf(rx * rx + ry * ry + rz * rz);
    rankArr[e] = atomicAdd(&cnt8[stripe * N_NODES + s], 1);
}

__global__ void fb_scan(const int* __restrict__ cnt8,
                        int* __restrict__ incl,
                        int* __restrict__ bsum) {
    __shared__ int sh[TPB];
    int tid = threadIdx.x;
    int i = blockIdx.x * TPB + tid;
    int tot = 0;
    if (i < N_NODES) {
#pragma unroll
        for (int c = 0; c < NSTRIPE; ++c) tot += cnt8[c * N_NODES + i];
    }
    sh[tid] = tot;
    __syncthreads();
    for (int s = 1; s < TPB; s <<= 1) {
        int x = 0;
        if (tid >= s) x = sh[tid - s];
        __syncthreads();
        if (tid >= s) sh[tid] += x;
        __syncthreads();
    }
    if (i < N_NODES) incl[i] = sh[tid];
    if (tid == TPB - 1) bsum[blockIdx.x] = sh[TPB - 1];
}

__global__ void fb_final(const int* __restrict__ cnt8,
                         const int* __restrict__ incl,
                         const int* __restrict__ bsum,
                         int* __restrict__ offsets,
                         int* __restrict__ copyBase) {
    __shared__ int sh[TPB];
    int tid = threadIdx.x;
    int b = blockIdx.x;
    sh[tid] = (tid < b) ? bsum[tid] : 0;
    __syncthreads();
    for (int s = 128; s > 0; s >>= 1) {
        if (tid < s) sh[tid] += sh[tid + s];
        __syncthreads();
    }
    int base = sh[0];
    int i = b * TPB + tid;
    if (i < N_NODES) {
        int cv[NSTRIPE];
        int tot = 0;
#pragma unroll
        for (int c = 0; c < NSTRIPE; ++c) { cv[c] = cnt8[c * N_NODES + i]; tot += cv[c]; }
        int off = base + incl[i] - tot;
        offsets[i] = off;
        int run = off;
#pragma unroll
        for (int c = 0; c < NSTRIPE; ++c) { copyBase[c * N_NODES + i] = run; run += cv[c]; }
    }
    if (b == 0 && tid == 0) offsets[N_NODES] = N_EDGES;
}

__global__ void fb_fill(const int* __restrict__ src,
                        const int* __restrict__ dst,
                        const float* __restrict__ pos,
                        const float* __restrict__ dists,
                        const int* __restrict__ copyBase,
                        const int* __restrict__ rankArr,
                        float4* __restrict__ edata,
                        int* __restrict__ csr) {
    int e = blockIdx.x * TPB + threadIdx.x;
    if (e >= N_EDGES) return;
    int stripe = blockIdx.x & (NSTRIPE - 1);
    int s = src[e];
    int d = dst[e];
    float rx = pos[3 * s + 0] - pos[3 * d + 0];
    float ry = pos[3 * s + 1] - pos[3 * d + 1];
    float rz = pos[3 * s + 2] - pos[3 * d + 2];
    float inv = 1.0f / dists[e];
    int slot = copyBase[stripe * N_NODES + s] + rankArr[e];
    float4 ed;
    ed.x = rx * inv;
    ed.y = ry * inv;
    ed.z = rz * inv;
    ed.w = __int_as_float(d);
    edata[slot] = ed;
    csr[slot] = e;
}

__global__ void fb_main(const float* __restrict__ h0,
                        const float* __restrict__ h1,
                        const float* __restrict__ h2,
                        const int* __restrict__ offsets,
                        const float4* __restrict__ edata,
                        const int* __restrict__ csr,
                        const float* __restrict__ dists,
                        float* __restrict__ out0,
                        float* __restrict__ out1,
                        float* __restrict__ out2) {
    int gid = blockIdx.x * TPB + threadIdx.x;
    int node = gid >> 6;
    if (node >= N_NODES) return;
    int lane = threadIdx.x & 63;
    int k = lane & 15;
    int j = lane >> 4;
    int beg = offsets[node];
    int end = offsets[node + 1];

    float acc0 = 0.0f;
    float acc1[3] = {0.0f, 0.0f, 0.0f};
    float acc2[9] = {0.0f, 0.0f, 0.0f, 0.0f, 0.0f, 0.0f, 0.0f, 0.0f, 0.0f};

    int i = beg + j;
    float4 ed;
    int e = 0;
    if (i < end) { ed = edata[i]; e = csr[i]; }
    while (i < end) {
        int inext = i + 4;
        float4 edn = ed;
        int en = e;
        if (inext < end) { edn = edata[inext]; en = csr[inext]; }

        int d = __float_as_int(ed.w);
        float a0, a1[3], a2[9], r, nf;
        load_hset(h0, h1, h2, dists, d, e, k, a0, a1, a2, r, nf);
        float R = radial_R(nf, r);
        edge_math(ed.x, ed.y, ed.z, R, a0, a1, a2, acc0, acc1, acc2);

        ed = edn;
        e = en;
        i = inext;
    }

    acc0 += __shfl_xor(acc0, 16, 64);
    acc0 += __shfl_xor(acc0, 32, 64);
#pragma unroll
    for (int mm = 0; mm < 3; ++mm) {
        acc1[mm] += __shfl_xor(acc1[mm], 16, 64);
        acc1[mm] += __shfl_xor(acc1[mm], 32, 64);
    }
#pragma unroll
    for (int mm = 0; mm < 9; ++mm) {
        acc2[mm] += __shfl_xor(acc2[mm], 16, 64);
        acc2[mm] += __shfl_xor(acc2[mm], 32, 64);
    }

    if (j == 0) {
        int t = node * NCH + k;
        out0[t] = acc0;
        float* o1p = out1 + (size_t)t * 3;
#pragma unroll
        for (int mm = 0; mm < 3; ++mm) o1p[mm] = acc1[mm];
        float* o2p = out2 + (size_t)t * 9;
#pragma unroll
        for (int mm = 0; mm < 9; ++mm) o2p[mm] = acc2[mm];
    }
}

// ======================= host =======================

extern "C" void kernel_launch(void* const* d_in, const int* in_sizes, int n_in,
                              void* d_out, int out_size, void* d_ws, size_t ws_size,
                              hipStream_t stream) {
    const float* h0  = (const float*)d_in[0];
    const float* h1  = (const float*)d_in[1];
    const float* h2  = (const float*)d_in[2];
    const float* pos = (const float*)d_in[3];
    // d_in[4] = channel_weights: dead in the reference dataflow
    const int* edge_index = (const int*)d_in[5];
    const int* src = edge_index;
    const int* dst = edge_index + N_EDGES;

    float* out = (float*)d_out;
    float* out0 = out;                                  // [N,16]
    float* out1 = out + (size_t)N_NODES * NCH;          // [N,16,3]
    float* out2 = out + (size_t)N_NODES * NCH * 4;      // [N,16,9]

    const size_t hpack_f4 = (size_t)N_NODES * NCH * 2;   // 1.6M float4 = 25.6 MB
    const size_t ebuf_n   = (size_t)N_NODES * CAP + EBUF_PAD;

    // Tier A: fp16 hpack + bucketed records (~46.6 MB)
    size_t needA = hpack_f4 * 16 + ebuf_n * 8
                 + (size_t)N_EDGES * 4 + (size_t)N_NODES * 4;
    // Tier B: round-3 path (~21 MB)
    size_t needB = ebuf_n * 8 + (size_t)N_EDGES * 4 + (size_t)N_NODES * 4;

    if (ws_size >= needA) {
        float4* hpack = (float4*)d_ws;                     // 25.6 MB
        int2* ebuf    = (int2*)(hpack + hpack_f4);         // 19.2 MB
        float* dists  = (float*)(ebuf + ebuf_n);           //  1.6 MB
        int* cnt      = (int*)(dists + N_EDGES);           //  0.2 MB

        hipMemsetAsync(cnt, 0, N_NODES * sizeof(int), stream);
        prep_kernel<<<NB_PREP, TPB, 0, stream>>>(h0, h1, h2, pos, src, dst,
                                                 hpack, dists, cnt, ebuf);
        node_wave_fast<<<NB_MAIN, TPB, 0, stream>>>(
            hpack, pos, cnt, ebuf, dists, out0, out1, out2);
    } else if (ws_size >= needB) {
        int2* ebuf   = (int2*)d_ws;
        float* dists = (float*)(ebuf + ebuf_n);
        int* cnt     = (int*)(dists + N_EDGES);

        hipMemsetAsync(cnt, 0, N_NODES * sizeof(int), stream);
        build_kernel<<<NB_EDGES, TPB, 0, stream>>>(pos, src, dst, dists, cnt, ebuf);
        node_wave_mid<<<(N_NODES * 64 + TPB - 1) / TPB, TPB, 0, stream>>>(
            h0, h1, h2, pos, cnt, ebuf, dists, out0, out1, out2);
    } else {
        // R8 pipeline (~15 MB ws)
        float4* edata   = (float4*)d_ws;                            // [E]
        float*  dists   = (float*)(edata + N_EDGES);                // [E]
        int* cnt8       = (int*)(dists + N_EDGES);                  // [8][N]
        int* rankArr    = cnt8 + NSTRIPE * N_NODES;                 // [E]
        int* incl       = rankArr + N_EDGES;                        // [N]
        int* bsum       = incl + N_NODES;                           // [NBN]
        int* offsets    = bsum + 256;                               // [N+1]
        int* copyBase   = offsets + N_NODES + 1;                    // [8][N]
        int* csr        = copyBase + NSTRIPE * N_NODES;             // [E]

        hipMemsetAsync(cnt8, 0, NSTRIPE * N_NODES * sizeof(int), stream);
        fb_geom_hist<<<NB_EDGES, TPB, 0, stream>>>(pos, src, dst, dists, cnt8, rankArr);
        fb_scan<<<NBN, TPB, 0, stream>>>(cnt8, incl, bsum);
        fb_final<<<NBN, TPB, 0, stream>>>(cnt8, incl, bsum, offsets, copyBase);
        fb_fill<<<NB_EDGES, TPB, 0, stream>>>(src, dst, pos, dists, copyBase, rankArr, edata, csr);
        fb_main<<<(N_NODES * 64 + TPB - 1) / TPB, TPB, 0, stream>>>(
            h0, h1, h2, offsets, edata, csr, dists, out0, out1, out2);
    }
}

// Round 12
// 166.278 us; speedup vs baseline: 1.0978x; 1.0978x over previous
//
#include <hip/hip_runtime.h>
#include <hip/hip_fp16.h>
#include <math.h>

#define N_NODES   50000
#define N_EDGES   400000
#define NCH       16
#define CAP       48          // per-node edge capacity; P(deg>48 | lambda=8) ~ 1e-17
#define EBUF_PAD  16          // slack slots so in-loop record prefetch never reads OOB
#define NSTRIPE   8
#define TPB       256
#define NBN       ((N_NODES + TPB - 1) / TPB)   // 196
#define NB_EDGES  ((N_EDGES + TPB - 1) / TPB)   // 1563
#define NB_PACK   ((N_NODES * NCH + TPB - 1) / TPB)  // 3125
#define NB_PREP   (NB_PACK + NB_EDGES)               // 4688

// ======================= FAST PATH (bucketed, 3 dispatches) =======================

// K0+K1 fused: blocks [0,NB_PACK) pack h into fp16 records; blocks
// [NB_PACK,NB_PREP) do per-edge geometry + bucket write. The two halves are
// independent (disjoint reads/writes) and overlap on the machine.
__global__ void prep_kernel(const float* __restrict__ h0,
                            const float* __restrict__ h1,
                            const float* __restrict__ h2,
                            const float* __restrict__ pos,
                            const int* __restrict__ src,
                            const int* __restrict__ dst,
                            float4* __restrict__ hpack,
                            float* __restrict__ dists,
                            int* __restrict__ cnt,
                            int2* __restrict__ ebuf) {
    int b = blockIdx.x;
    if (b < NB_PACK) {
        // ---- pack: one (node,k) per thread -> 32B fp16 record ----
        int nk = b * TPB + threadIdx.x;
        if (nk >= N_NODES * NCH) return;
        union { __half h[16]; float4 f[2]; } u;
        u.h[0] = __float2half(h0[nk]);
        const float* p1 = h1 + (size_t)nk * 3;
        u.h[1] = __float2half(p1[0]);
        u.h[2] = __float2half(p1[1]);
        u.h[3] = __float2half(p1[2]);
        const float* p2 = h2 + (size_t)nk * 9;
#pragma unroll
        for (int q = 0; q < 9; ++q) u.h[4 + q] = __float2half(p2[q]);
        u.h[13] = __half(0.0f);
        u.h[14] = __half(0.0f);
        u.h[15] = __half(0.0f);
        float4* o = hpack + (size_t)nk * 2;
        o[0] = u.f[0];
        o[1] = u.f[1];
    } else {
        // ---- build: per-edge dist + slim 8B bucket record {e, d} ----
        int e = (b - NB_PACK) * TPB + threadIdx.x;
        if (e >= N_EDGES) return;
        int s = src[e];
        int d = dst[e];
        float rx = pos[3 * s + 0] - pos[3 * d + 0];
        float ry = pos[3 * s + 1] - pos[3 * d + 1];
        float rz = pos[3 * s + 2] - pos[3 * d + 2];
        float dist = sqrtf(rx * rx + ry * ry + rz * rz);
        dists[e] = dist;
        int slot = atomicAdd(&cnt[s], 1);
        if (slot < CAP) {
            ebuf[s * CAP + slot] = make_int2(e, d);
        }
    }
}

// standalone build (tier B path, no hpack)
__global__ void build_kernel(const float* __restrict__ pos,
                             const int* __restrict__ src,
                             const int* __restrict__ dst,
                             float* __restrict__ dists,
                             int* __restrict__ cnt,
                             int2* __restrict__ ebuf) {
    int e = blockIdx.x * TPB + threadIdx.x;
    if (e >= N_EDGES) return;
    int s = src[e];
    int d = dst[e];
    float rx = pos[3 * s + 0] - pos[3 * d + 0];
    float ry = pos[3 * s + 1] - pos[3 * d + 1];
    float rz = pos[3 * s + 2] - pos[3 * d + 2];
    float dist = sqrtf(rx * rx + ry * ry + rz * rz);
    dists[e] = dist;
    int slot = atomicAdd(&cnt[s], 1);
    if (slot < CAP) {
        ebuf[s * CAP + slot] = make_int2(e, d);
    }
}

// ---- per-edge math, FACTORED form (all terms linear in R; row factors hoisted).
// Mathematically identical to the verified expansion up to fp32 reassociation.
__device__ __forceinline__ void edge_math(
    float ux, float uy, float uz, float R,
    float A0, const float A1[3], const float A2[9],
    float& acc0, float acc1[3], float acc2[9])
{
    float u[3] = {ux, uy, uz};
    float d1 = A1[0] * ux + A1[1] * uy + A1[2] * uz;   // A1.u
    float tA = A2[0] + A2[4] + A2[8];                   // tr(A2)
    float v0 = A2[0] * ux + A2[1] * uy + A2[2] * uz;    // A2 u
    float v1 = A2[3] * ux + A2[4] * uy + A2[5] * uz;
    float v2 = A2[6] * ux + A2[7] * uy + A2[8] * uz;
    float w0 = A2[0] * ux + A2[3] * uy + A2[6] * uz;    // A2^T u
    float w1 = A2[1] * ux + A2[4] * uy + A2[7] * uz;
    float w2 = A2[2] * ux + A2[5] * uy + A2[8] * uz;
    float q = ux * v0 + uy * v1 + uz * v2;              // u^T A2 u

    // acc0 += R*(2A0 + d1 + 2tA + 2q)
    acc0 += R * (2.0f * A0 + d1 + 2.0f * tA + 2.0f * q);

    float svw[3] = {v0 + w0, v1 + w1, v2 + w2};
    float R2 = R + R;
    float a0t = A0 + tA;
    // acc1[m] += R*((A0 + 2*d1 + tA)*u[m]) + 2R*A1[m] + R*svw[m]
    float Rc1 = R * (a0t + 2.0f * d1);
#pragma unroll
    for (int mm = 0; mm < 3; ++mm) {
        acc1[mm] = fmaf(Rc1, u[mm], acc1[mm]);
        acc1[mm] = fmaf(R2, A1[mm], acc1[mm]);
        acc1[mm] = fmaf(R, svw[mm], acc1[mm]);
    }
    // acc2[m][n] += g[m]*u[n] + 2R*A2[m][n],  g[m] = R*(a0t*u[m] + A1[m] + 2*svw[m])
#pragma unroll
    for (int mm = 0; mm < 3; ++mm) {
        float t1 = fmaf(2.0f, svw[mm], A1[mm]);
        float g = R * fmaf(a0t, u[mm], t1);
#pragma unroll
        for (int nn = 0; nn < 3; ++nn) {
            float a = acc2[3 * mm + nn];
            a = fmaf(g, u[nn], a);
            a = fmaf(R2, A2[3 * mm + nn], a);
            acc2[3 * mm + nn] = a;
        }
    }
}

// ---- fallback-path helpers ----
__device__ __forceinline__ void load_hset(
    const float* __restrict__ h0, const float* __restrict__ h1,
    const float* __restrict__ h2, const float* __restrict__ dists,
    int d, int e, int k,
    float& A0, float A1[3], float A2[9], float& r, float& nf)
{
    A0 = h0[d * NCH + k];
    const float* p1 = h1 + ((size_t)d * NCH + k) * 3;
    A1[0] = p1[0]; A1[1] = p1[1]; A1[2] = p1[2];
    const float* p2 = h2 + ((size_t)d * NCH + k) * 9;
#pragma unroll
    for (int q2 = 0; q2 < 9; ++q2) A2[q2] = p2[q2];
    unsigned f = (unsigned)e * NCH + (unsigned)k;
    unsigned n_idx = f / (unsigned)N_EDGES;
    unsigned e_idx = f - n_idx * (unsigned)N_EDGES;
    r = dists[e_idx];
    nf = (float)(n_idx + 1);
}

__device__ __forceinline__ float radial_R(float nf, float r) {
    return 0.44721359549995794f * __sinf(nf * 0.3141592653589793f * r) / r;
}

// K2 (tier A): one wave per node (lane = j*16+k), round-3/5/6 loop discipline,
// fp16 hpack gather: 2x dwordx4 + 3 L2-hot pos scalars + 1 dists + 1 record.
__global__ void node_wave_fast(const float4* __restrict__ hp,
                               const float* __restrict__ pos,
                               const int* __restrict__ cnt,
                               const int2* __restrict__ ebuf,
                               const float* __restrict__ dists,
                               float* __restrict__ out0,
                               float* __restrict__ out1,
                               float* __restrict__ out2) {
    int gid = blockIdx.x * TPB + threadIdx.x;
    int node = gid >> 6;
    if (node >= N_NODES) return;
    int lane = threadIdx.x & 63;
    int k = lane & 15;
    int j = lane >> 4;
    int base = node * CAP;

    // node-entry: cnt + first record + own pos, all independent
    int m = cnt[node];
    int2 pk = ebuf[base + j];                  // j<4<CAP: always in row
    float ps0 = pos[3 * node + 0];
    float ps1 = pos[3 * node + 1];
    float ps2 = pos[3 * node + 2];
    if (m > CAP) m = CAP;

    float acc0 = 0.0f;
    float acc1[3] = {0.0f, 0.0f, 0.0f};
    float acc2[9] = {0.0f, 0.0f, 0.0f, 0.0f, 0.0f, 0.0f, 0.0f, 0.0f, 0.0f};

    int c = j;
    while (c < m) {
        int cn = c + 4;
        int2 pkn = ebuf[base + cn];    // EBUF_PAD: always readable; gated by cn<m

        int e = pk.x;
        int d = pk.y;

        // fp16 h record: 32B = 2x dwordx4
        size_t hb = ((size_t)((d << 4) | k)) * 2;
        union { float4 f[2]; __half h[16]; } u;
        u.f[0] = hp[hb + 0];
        u.f[1] = hp[hb + 1];

        // neighbor position (L2-resident 600KB table, fp32 for cancellation)
        float pd0 = pos[3 * d + 0];
        float pd1 = pos[3 * d + 1];
        float pd2 = pos[3 * d + 2];

        // radial with the reference's faithful [K,E]->[E,K] reshape
        unsigned f = (unsigned)e * NCH + (unsigned)k;
        unsigned n_idx = f / (unsigned)N_EDGES;
        unsigned e_idx = f - n_idx * (unsigned)N_EDGES;
        float r = dists[e_idx];
        float R = 0.44721359549995794f *
                  __sinf((float)(n_idx + 1) * 0.3141592653589793f * r) *
                  __builtin_amdgcn_rcpf(r);

        float rx = ps0 - pd0;
        float ry = ps1 - pd1;
        float rz = ps2 - pd2;
        float s2 = rx * rx + ry * ry + rz * rz;
        float inv = __builtin_amdgcn_rsqf(s2);

        float A0 = __half2float(u.h[0]);
        float A1[3] = {__half2float(u.h[1]), __half2float(u.h[2]),
                       __half2float(u.h[3])};
        float A2[9];
#pragma unroll
        for (int q2 = 0; q2 < 9; ++q2) A2[q2] = __half2float(u.h[4 + q2]);

        edge_math(rx * inv, ry * inv, rz * inv, R, A0, A1, A2,
                  acc0, acc1, acc2);

        pk = pkn;
        c = cn;
    }

    // reduce across j (lanes xor 16, xor 32)
    acc0 += __shfl_xor(acc0, 16, 64);
    acc0 += __shfl_xor(acc0, 32, 64);
#pragma unroll
    for (int mm = 0; mm < 3; ++mm) {
        acc1[mm] += __shfl_xor(acc1[mm], 16, 64);
        acc1[mm] += __shfl_xor(acc1[mm], 32, 64);
    }
#pragma unroll
    for (int mm = 0; mm < 9; ++mm) {
        acc2[mm] += __shfl_xor(acc2[mm], 16, 64);
        acc2[mm] += __shfl_xor(acc2[mm], 32, 64);
    }

    if (j == 0) {
        int t = node * NCH + k;
        out0[t] = acc0;
        float* o1p = out1 + (size_t)t * 3;
#pragma unroll
        for (int mm = 0; mm < 3; ++mm) o1p[mm] = acc1[mm];
        float* o2p = out2 + (size_t)t * 9;
#pragma unroll
        for (int mm = 0; mm < 9; ++mm) o2p[mm] = acc2[mm];
    }
}

// K2 (tier B): round-3 kernel — unpacked fp32 gather, smaller workspaces.
__global__ void node_wave_mid(const float* __restrict__ h0,
                              const float* __restrict__ h1,
                              const float* __restrict__ h2,
                              const float* __restrict__ pos,
                              const int* __restrict__ cnt,
                              const int2* __restrict__ ebuf,
                              const float* __restrict__ dists,
                              float* __restrict__ out0,
                              float* __restrict__ out1,
                              float* __restrict__ out2) {
    int gid = blockIdx.x * TPB + threadIdx.x;
    int node = gid >> 6;
    if (node >= N_NODES) return;
    int lane = threadIdx.x & 63;
    int k = lane & 15;
    int j = lane >> 4;
    int base = node * CAP;

    int m = cnt[node];
    int2 pk = ebuf[base + j];
    float ps0 = pos[3 * node + 0];
    float ps1 = pos[3 * node + 1];
    float ps2 = pos[3 * node + 2];
    if (m > CAP) m = CAP;

    float acc0 = 0.0f;
    float acc1[3] = {0.0f, 0.0f, 0.0f};
    float acc2[9] = {0.0f, 0.0f, 0.0f, 0.0f, 0.0f, 0.0f, 0.0f, 0.0f, 0.0f};

    int c = j;
    while (c < m) {
        int cn = c + 4;
        int2 pkn = pk;
        if (cn < m) pkn = ebuf[base + cn];

        int e = pk.x;
        int d = pk.y;

        float pd0 = pos[3 * d + 0];
        float pd1 = pos[3 * d + 1];
        float pd2 = pos[3 * d + 2];

        float A0 = h0[d * NCH + k];
        const float* a1p = h1 + ((size_t)d * NCH + k) * 3;
        float A1[3] = {a1p[0], a1p[1], a1p[2]};
        const float* a2p = h2 + ((size_t)d * NCH + k) * 9;
        float A2[9];
#pragma unroll
        for (int q2 = 0; q2 < 9; ++q2) A2[q2] = a2p[q2];

        unsigned f = (unsigned)e * NCH + (unsigned)k;
        unsigned n_idx = f / (unsigned)N_EDGES;
        unsigned e_idx = f - n_idx * (unsigned)N_EDGES;
        float r = dists[e_idx];
        float R = 0.44721359549995794f *
                  __sinf((float)(n_idx + 1) * 0.3141592653589793f * r) / r;

        float rx = ps0 - pd0;
        float ry = ps1 - pd1;
        float rz = ps2 - pd2;
        float dist = sqrtf(rx * rx + ry * ry + rz * rz);
        float inv = 1.0f / dist;

        edge_math(rx * inv, ry * inv, rz * inv, R, A0, A1, A2, acc0, acc1, acc2);

        pk = pkn;
        c = cn;
    }

    acc0 += __shfl_xor(acc0, 16, 64);
    acc0 += __shfl_xor(acc0, 32, 64);
#pragma unroll
    for (int mm = 0; mm < 3; ++mm) {
        acc1[mm] += __shfl_xor(acc1[mm], 16, 64);
        acc1[mm] += __shfl_xor(acc1[mm], 32, 64);
    }
#pragma unroll
    for (int mm = 0; mm < 9; ++mm) {
        acc2[mm] += __shfl_xor(acc2[mm], 16, 64);
        acc2[mm] += __shfl_xor(acc2[mm], 32, 64);
    }

    if (j == 0) {
        int t = node * NCH + k;
        out0[t] = acc0;
        float* o1p = out1 + (size_t)t * 3;
#pragma unroll
        for (int mm = 0; mm < 3; ++mm) o1p[mm] = acc1[mm];
        float* o2p = out2 + (size_t)t * 9;
#pragma unroll
        for (int mm = 0; mm < 9; ++mm) o2p[mm] = acc2[mm];
    }
}

// ======================= FALLBACK (R8 pipeline, small ws) =======================

__global__ void fb_geom_hist(const float* __restrict__ pos,
                             const int* __restrict__ src,
                             const int* __restrict__ dst,
                             float* __restrict__ dists,
                             int* __restrict__ cnt8,
                             int* __restrict__ rankArr) {
    int e = blockIdx.x * TPB + threadIdx.x;
    if (e >= N_EDGES) return;
    int stripe = blockIdx.x & (NSTRIPE - 1);
    int s = src[e];
    int d = dst[e];
    float rx = pos[3 * s + 0] - pos[3 * d + 0];
    float ry = pos[3 * s + 1] - pos[3 * d + 1];
    float rz = pos[3 * s + 2] - pos[3 * d + 2];
    dists[e] = sqrtf(rx * rx + ry * ry + rz * rz);
    rankArr[e] = atomicAdd(&cnt8[stripe * N_NODES + s], 1);
}

__global__ void fb_scan(const int* __restrict__ cnt8,
                        int* __restrict__ incl,
                        int* __restrict__ bsum) {
    __shared__ int sh[TPB];
    int tid = threadIdx.x;
    int i = blockIdx.x * TPB + tid;
    int tot = 0;
    if (i < N_NODES) {
#pragma unroll
        for (int c = 0; c < NSTRIPE; ++c) tot += cnt8[c * N_NODES + i];
    }
    sh[tid] = tot;
    __syncthreads();
    for (int s = 1; s < TPB; s <<= 1) {
        int x = 0;
        if (tid >= s) x = sh[tid - s];
        __syncthreads();
        if (tid >= s) sh[tid] += x;
        __syncthreads();
    }
    if (i < N_NODES) incl[i] = sh[tid];
    if (tid == TPB - 1) bsum[blockIdx.x] = sh[TPB - 1];
}

__global__ void fb_final(const int* __restrict__ cnt8,
                         const int* __restrict__ incl,
                         const int* __restrict__ bsum,
                         int* __restrict__ offsets,
                         int* __restrict__ copyBase) {
    __shared__ int sh[TPB];
    int tid = threadIdx.x;
    int b = blockIdx.x;
    sh[tid] = (tid < b) ? bsum[tid] : 0;
    __syncthreads();
    for (int s = 128; s > 0; s >>= 1) {
        if (tid < s) sh[tid] += sh[tid + s];
        __syncthreads();
    }
    int base = sh[0];
    int i = b * TPB + tid;
    if (i < N_NODES) {
        int cv[NSTRIPE];
        int tot = 0;
#pragma unroll
        for (int c = 0; c < NSTRIPE; ++c) { cv[c] = cnt8[c * N_NODES + i]; tot += cv[c]; }
        int off = base + incl[i] - tot;
        offsets[i] = off;
        int run = off;
#pragma unroll
        for (int c = 0; c < NSTRIPE; ++c) { copyBase[c * N_NODES + i] = run; run += cv[c]; }
    }
    if (b == 0 && tid == 0) offsets[N_NODES] = N_EDGES;
}

__global__ void fb_fill(const int* __restrict__ src,
                        const int* __restrict__ dst,
                        const float* __restrict__ pos,
                        const float* __restrict__ dists,
                        const int* __restrict__ copyBase,
                        const int* __restrict__ rankArr,
                        float4* __restrict__ edata,
                        int* __restrict__ csr) {
    int e = blockIdx.x * TPB + threadIdx.x;
    if (e >= N_EDGES) return;
    int stripe = blockIdx.x & (NSTRIPE - 1);
    int s = src[e];
    int d = dst[e];
    float rx = pos[3 * s + 0] - pos[3 * d + 0];
    float ry = pos[3 * s + 1] - pos[3 * d + 1];
    float rz = pos[3 * s + 2] - pos[3 * d + 2];
    float inv = 1.0f / dists[e];
    int slot = copyBase[stripe * N_NODES + s] + rankArr[e];
    float4 ed;
    ed.x = rx * inv;
    ed.y = ry * inv;
    ed.z = rz * inv;
    ed.w = __int_as_float(d);
    edata[slot] = ed;
    csr[slot] = e;
}

__global__ void fb_main(const float* __restrict__ h0,
                        const float* __restrict__ h1,
                        const float* __restrict__ h2,
                        const int* __restrict__ offsets,
                        const float4* __restrict__ edata,
                        const int* __restrict__ csr,
                        const float* __restrict__ dists,
                        float* __restrict__ out0,
                        float* __restrict__ out1,
                        float* __restrict__ out2) {
    int gid = blockIdx.x * TPB + threadIdx.x;
    int node = gid >> 6;
    if (node >= N_NODES) return;
    int lane = threadIdx.x & 63;
    int k = lane & 15;
    int j = lane >> 4;
    int beg = offsets[node];
    int end = offsets[node + 1];

    float acc0 = 0.0f;
    float acc1[3] = {0.0f, 0.0f, 0.0f};
    float acc2[9] = {0.0f, 0.0f, 0.0f, 0.0f, 0.0f, 0.0f, 0.0f, 0.0f, 0.0f};

    int i = beg + j;
    float4 ed;
    int e = 0;
    if (i < end) { ed = edata[i]; e = csr[i]; }
    while (i < end) {
        int inext = i + 4;
        float4 edn = ed;
        int en = e;
        if (inext < end) { edn = edata[inext]; en = csr[inext]; }

        int d = __float_as_int(ed.w);
        float a0, a1[3], a2[9], r, nf;
        load_hset(h0, h1, h2, dists, d, e, k, a0, a1, a2, r, nf);
        float R = radial_R(nf, r);
        edge_math(ed.x, ed.y, ed.z, R, a0, a1, a2, acc0, acc1, acc2);

        ed = edn;
        e = en;
        i = inext;
    }

    acc0 += __shfl_xor(acc0, 16, 64);
    acc0 += __shfl_xor(acc0, 32, 64);
#pragma unroll
    for (int mm = 0; mm < 3; ++mm) {
        acc1[mm] += __shfl_xor(acc1[mm], 16, 64);
        acc1[mm] += __shfl_xor(acc1[mm], 32, 64);
    }
#pragma unroll
    for (int mm = 0; mm < 9; ++mm) {
        acc2[mm] += __shfl_xor(acc2[mm], 16, 64);
        acc2[mm] += __shfl_xor(acc2[mm], 32, 64);
    }

    if (j == 0) {
        int t = node * NCH + k;
        out0[t] = acc0;
        float* o1p = out1 + (size_t)t * 3;
#pragma unroll
        for (int mm = 0; mm < 3; ++mm) o1p[mm] = acc1[mm];
        float* o2p = out2 + (size_t)t * 9;
#pragma unroll
        for (int mm = 0; mm < 9; ++mm) o2p[mm] = acc2[mm];
    }
}

// ======================= host =======================

extern "C" void kernel_launch(void* const* d_in, const int* in_sizes, int n_in,
                              void* d_out, int out_size, void* d_ws, size_t ws_size,
                              hipStream_t stream) {
    const float* h0  = (const float*)d_in[0];
    const float* h1  = (const float*)d_in[1];
    const float* h2  = (const float*)d_in[2];
    const float* pos = (const float*)d_in[3];
    // d_in[4] = channel_weights: dead in the reference dataflow
    const int* edge_index = (const int*)d_in[5];
    const int* src = edge_index;
    const int* dst = edge_index + N_EDGES;

    float* out = (float*)d_out;
    float* out0 = out;                                  // [N,16]
    float* out1 = out + (size_t)N_NODES * NCH;          // [N,16,3]
    float* out2 = out + (size_t)N_NODES * NCH * 4;      // [N,16,9]

    const size_t hpack_f4 = (size_t)N_NODES * NCH * 2;   // 1.6M float4 = 25.6 MB
    const size_t ebuf_n   = (size_t)N_NODES * CAP + EBUF_PAD;

    // Tier A: fp16 hpack + bucketed records (~46.6 MB)
    size_t needA = hpack_f4 * 16 + ebuf_n * 8
                 + (size_t)N_EDGES * 4 + (size_t)N_NODES * 4;
    // Tier B: round-3 path (~21 MB)
    size_t needB = ebuf_n * 8 + (size_t)N_EDGES * 4 + (size_t)N_NODES * 4;

    if (ws_size >= needA) {
        float4* hpack = (float4*)d_ws;                     // 25.6 MB
        int2* ebuf    = (int2*)(hpack + hpack_f4);         // 19.2 MB
        float* dists  = (float*)(ebuf + ebuf_n);           //  1.6 MB
        int* cnt      = (int*)(dists + N_EDGES);           //  0.2 MB

        hipMemsetAsync(cnt, 0, N_NODES * sizeof(int), stream);
        prep_kernel<<<NB_PREP, TPB, 0, stream>>>(h0, h1, h2, pos, src, dst,
                                                 hpack, dists, cnt, ebuf);
        node_wave_fast<<<(N_NODES * 64 + TPB - 1) / TPB, TPB, 0, stream>>>(
            hpack, pos, cnt, ebuf, dists, out0, out1, out2);
    } else if (ws_size >= needB) {
        int2* ebuf   = (int2*)d_ws;
        float* dists = (float*)(ebuf + ebuf_n);
        int* cnt     = (int*)(dists + N_EDGES);

        hipMemsetAsync(cnt, 0, N_NODES * sizeof(int), stream);
        build_kernel<<<NB_EDGES, TPB, 0, stream>>>(pos, src, dst, dists, cnt, ebuf);
        node_wave_mid<<<(N_NODES * 64 + TPB - 1) / TPB, TPB, 0, stream>>>(
            h0, h1, h2, pos, cnt, ebuf, dists, out0, out1, out2);
    } else {
        // R8 pipeline (~15 MB ws)
        float4* edata   = (float4*)d_ws;                            // [E]
        float*  dists   = (float*)(edata + N_EDGES);                // [E]
        int* cnt8       = (int*)(dists + N_EDGES);                  // [8][N]
        int* rankArr    = cnt8 + NSTRIPE * N_NODES;                 // [E]
        int* incl       = rankArr + N_EDGES;                        // [N]
        int* bsum       = incl + N_NODES;                           // [NBN]
        int* offsets    = bsum + 256;                               // [N+1]
        int* copyBase   = offsets + N_NODES + 1;                    // [8][N]
        int* csr        = copyBase + NSTRIPE * N_NODES;             // [E]

        hipMemsetAsync(cnt8, 0, NSTRIPE * N_NODES * sizeof(int), stream);
        fb_geom_hist<<<NB_EDGES, TPB, 0, stream>>>(pos, src, dst, dists, cnt8, rankArr);
        fb_scan<<<NBN, TPB, 0, stream>>>(cnt8, incl, bsum);
        fb_final<<<NBN, TPB, 0, stream>>>(cnt8, incl, bsum, offsets, copyBase);
        fb_fill<<<NB_EDGES, TPB, 0, stream>>>(src, dst, pos, dists, copyBase, rankArr, edata, csr);
        fb_main<<<(N_NODES * 64 + TPB - 1) / TPB, TPB, 0, stream>>>(
            h0, h1, h2, offsets, edata, csr, dists, out0, out1, out2);
    }
}